// Round 12
// baseline (518.937 us; speedup 1.0000x reference)
//
#include <hip/hip_runtime.h>
#include <hip/hip_bf16.h>

typedef unsigned short u16;
typedef unsigned int u32;
typedef short bf16x8 __attribute__((ext_vector_type(8)));
typedef float f32x4 __attribute__((ext_vector_type(4)));

#define MFMA_BF16 __builtin_amdgcn_mfma_f32_16x16x32_bf16

#define B_   2
#define S_   2048
#define E_   2048
#define H_   16
#define KVH_ 4
#define D_   128
#define M_   (B_ * S_)
#define NQKV 3072
#define SCALE_ 0.08838834764831845f  // 1/sqrt(128)

__device__ __forceinline__ float b2f(u16 u) {
    union { u32 i; float f; } x; x.i = ((u32)u) << 16; return x.f;
}
__device__ __forceinline__ u16 f2b(float f) {
    __hip_bfloat16 h = __float2bfloat16(f);
    return *reinterpret_cast<u16*>(&h);
}

// async 16B global->LDS: HW writes lds_base + lane*16  [m97 pattern]
__device__ __forceinline__ void async16(const u16* g, u16* l) {
    __builtin_amdgcn_global_load_lds(
        (const __attribute__((address_space(1))) void*)g,
        (__attribute__((address_space(3))) void*)l, 16, 0, 0);
}

__device__ __forceinline__ uint4 pack8(const float* p) {
    float4 a = *reinterpret_cast<const float4*>(p);
    float4 b = *reinterpret_cast<const float4*>(p + 4);
    union { uint4 v; u16 h[8]; } pk;
    pk.h[0] = f2b(a.x); pk.h[1] = f2b(a.y); pk.h[2] = f2b(a.z); pk.h[3] = f2b(a.w);
    pk.h[4] = f2b(b.x); pk.h[5] = f2b(b.y); pk.h[6] = f2b(b.z); pk.h[7] = f2b(b.w);
    return pk.v;
}

// ---------------------------------------------------------------------------
// f32 -> bf16 bulk convert, up to 4 regions per launch (2048 elems/block).
// ---------------------------------------------------------------------------
__global__ __launch_bounds__(256)
void conv4(const float* __restrict__ s0, u16* __restrict__ d0, int n0,
           const float* __restrict__ s1, u16* __restrict__ d1, int n1,
           const float* __restrict__ s2, u16* __restrict__ d2, int n2,
           const float* __restrict__ s3, u16* __restrict__ d3) {
    int bid = blockIdx.x;
    const float* s; u16* d; size_t base;
    if (bid < n0)                { s = s0; d = d0; base = (size_t)bid * 2048; }
    else if (bid < n0 + n1)      { s = s1; d = d1; base = (size_t)(bid - n0) * 2048; }
    else if (bid < n0 + n1 + n2) { s = s2; d = d2; base = (size_t)(bid - n0 - n1) * 2048; }
    else                         { s = s3; d = d3; base = (size_t)(bid - n0 - n1 - n2) * 2048; }
    size_t i = base + (size_t)threadIdx.x * 8;
    *reinterpret_cast<uint4*>(d + i) = pack8(s + i);
}

// ---------------------------------------------------------------------------
// Kernel 1: fused QKV gemm_bt + RoPE.  Split-barrier DOUBLE-BUFFERED LDS:
// per K-iter issue next tile's async16 FIRST, compute current, then one
// barrier (its vmcnt(0) drain lands after ~compute-length of overlap).
// Fragment-major LDS (conflict-free).  128x128 tile, BK=64, 64 KB LDS.
// ---------------------------------------------------------------------------
__global__ __launch_bounds__(256)
void qkv_rope_gemm(const u16* __restrict__ xb, const u16* __restrict__ wqb,
                   const u16* __restrict__ wkb, const u16* __restrict__ wvb,
                   const float* __restrict__ fc, const float* __restrict__ fs,
                   u16* __restrict__ Qr, u16* __restrict__ Kr,
                   u16* __restrict__ Vr) {
    __shared__ __align__(16) u16 As[2][8192];
    __shared__ __align__(16) u16 Bs[2][8192];
    const int tid = threadIdx.x, wave = tid >> 6, lane = tid & 63;
    const int l15 = lane & 15, quad = lane >> 4;
    const int wm = wave & 1, wn = wave >> 1;
    const int m0 = blockIdx.y * 128, n0 = blockIdx.x * 128;

    const u16* wsel;
    if (n0 < 2048)      wsel = wqb + (size_t)n0 * E_;
    else if (n0 < 2560) wsel = wkb + (size_t)(n0 - 2048) * E_;
    else                wsel = wvb + (size_t)(n0 - 2560) * E_;

    // per-thread staging source offsets (t = wave*4+j)
    size_t aoff[4], boff[4];
    #pragma unroll
    for (int j = 0; j < 4; ++j) {
        int t = wave * 4 + j;
        int row = (t >> 1) * 16 + l15;
        int col = (t & 1) * 32 + quad * 8;
        aoff[j] = (size_t)(m0 + row) * E_ + col;
        boff[j] = (size_t)row * E_ + col;
    }

    f32x4 acc[4][4];
    const f32x4 zero4 = {0.f, 0.f, 0.f, 0.f};
    for (int i = 0; i < 4; ++i)
        for (int j = 0; j < 4; ++j) acc[i][j] = zero4;

    // prologue: stage kt=0 into buf 0
    #pragma unroll
    for (int j = 0; j < 4; ++j) {
        int t = wave * 4 + j;
        async16(xb + aoff[j], &As[0][t * 512]);
        async16(wsel + boff[j], &Bs[0][t * 512]);
    }
    __syncthreads();

    for (int it = 0; it < 32; ++it) {
        const int cur = it & 1, nxt = cur ^ 1;
        if (it < 31) {                       // prefetch next tile (no wait)
            const size_t koff = (size_t)(it + 1) * 64;
            #pragma unroll
            for (int j = 0; j < 4; ++j) {
                int t = wave * 4 + j;
                async16(xb + aoff[j] + koff, &As[nxt][t * 512]);
                async16(wsel + boff[j] + koff, &Bs[nxt][t * 512]);
            }
        }
        #pragma unroll
        for (int kb = 0; kb < 2; ++kb) {
            bf16x8 af[4], bfr[4];
            #pragma unroll
            for (int i = 0; i < 4; ++i) {
                af[i]  = *reinterpret_cast<const bf16x8*>(
                    &As[cur][(((wm * 4 + i) << 1) | kb) * 512 + lane * 8]);
                bfr[i] = *reinterpret_cast<const bf16x8*>(
                    &Bs[cur][(((wn * 4 + i) << 1) | kb) * 512 + lane * 8]);
            }
            #pragma unroll
            for (int mi = 0; mi < 4; ++mi)
                #pragma unroll
                for (int ni = 0; ni < 4; ++ni)
                    acc[mi][ni] = MFMA_BF16(af[mi], bfr[ni], acc[mi][ni], 0, 0, 0);
        }
        __syncthreads();   // drains prefetch (issued before compute) + read-done
    }

    // epilogue: RoPE (pair partner in adjacent lane) + scatter
    const int mb_ = m0 + wm * 64, nbase = n0 + wn * 64;
    #pragma unroll
    for (int mi = 0; mi < 4; ++mi)
        #pragma unroll
        for (int ni = 0; ni < 4; ++ni)
            #pragma unroll
            for (int r = 0; r < 4; ++r) {
                int m = mb_ + mi * 16 + quad * 4 + r;   // C/D: row=quad*4+reg
                int n = nbase + ni * 16 + l15;          //      col=lane&15
                int b = m >> 11, s = m & 2047;
                float v = acc[mi][ni][r];
                float other = __shfl_xor(v, 1);
                if (n < 2560) {                          // rope on q and k
                    int d = n & 127;
                    int fi = s * 64 + (d >> 1);
                    float c  = fc[fi];
                    float sn = fs[fi];
                    v = (n & 1) ? (other * sn + v * c) : (v * c - other * sn);
                }
                if (n < 2048) {
                    Qr[((size_t)(b * H_ + (n >> 7)) * S_ + s) * D_ + (n & 127)] = f2b(v);
                } else if (n < 2560) {
                    int kh = (n - 2048) >> 7;
                    Kr[((size_t)(b * KVH_ + kh) * S_ + s) * D_ + (n & 127)] = f2b(v);
                } else {
                    int kh = (n - 2560) >> 7;
                    Vr[((size_t)(b * KVH_ + kh) * S_ + s) * D_ + (n & 127)] = f2b(v);
                }
            }
}

// ---------------------------------------------------------------------------
// Kernel 1.7: V transpose per (b,kvh): Vr[s][d] -> VrT[d][s].
// ---------------------------------------------------------------------------
__global__ __launch_bounds__(256)
void transpose_v(const u16* __restrict__ Vr, u16* __restrict__ VrT) {
    __shared__ u16 t[64][72];
    const int tid = threadIdx.x;
    const int s0 = blockIdx.x * 64, d0 = blockIdx.y * 64, g = blockIdx.z;
    const u16* src = Vr + (size_t)g * S_ * D_;
    u16* dst = VrT + (size_t)g * D_ * S_;
    #pragma unroll
    for (int i = 0; i < 2; ++i) {
        int c = tid + i * 256;
        int r = c >> 3, cc = (c & 7) * 8;
        *reinterpret_cast<uint4*>(&t[r][cc]) =
            *reinterpret_cast<const uint4*>(src + (size_t)(s0 + r) * D_ + d0 + cc);
    }
    __syncthreads();
    #pragma unroll
    for (int i = 0; i < 2; ++i) {
        int c = tid + i * 256;
        int r = c >> 3, cc = (c & 7) * 8;
        u16 tmp[8];
        #pragma unroll
        for (int e = 0; e < 8; ++e) tmp[e] = t[cc + e][r];
        *reinterpret_cast<uint4*>(dst + (size_t)(d0 + r) * S_ + s0 + cc) =
            *reinterpret_cast<const uint4*>(tmp);
    }
}

// ---------------------------------------------------------------------------
// Kernel 2: transposed causal flash attention (unchanged from R10/R11).
// ---------------------------------------------------------------------------
__global__ __launch_bounds__(512, 4)
void flash2(const u16* __restrict__ Qr, const u16* __restrict__ Kr,
            const u16* __restrict__ VrT, u16* __restrict__ AO) {
    __shared__ __align__(16) u16 Ks[64 * 128];
    __shared__ __align__(16) u16 Vs[128 * 64];
    const int tid = threadIdx.x, wave = tid >> 6, lane = tid & 63;
    const int l15 = lane & 15, quad = lane >> 4;
    const int qt = blockIdx.x, h = blockIdx.y, b = blockIdx.z;
    const int kvh = h & 3;                        // jnp.tile mapping
    const u16* Qb = Qr + (size_t)(b * H_ + h) * S_ * D_;
    const u16* Kb = Kr + (size_t)(b * KVH_ + kvh) * S_ * D_;
    const u16* Vb = VrT + (size_t)(b * KVH_ + kvh) * D_ * S_;
    const int q0 = qt * 128 + wave * 16;
    const int qg = q0 + l15;

    bf16x8 bq[4];
    #pragma unroll
    for (int kk = 0; kk < 4; ++kk)
        bq[kk] = *reinterpret_cast<const bf16x8*>(
            Qb + (size_t)qg * D_ + kk * 32 + quad * 8);

    f32x4 o[8];
    const f32x4 zero4 = {0.f, 0.f, 0.f, 0.f};
    #pragma unroll
    for (int i = 0; i < 8; ++i) o[i] = zero4;
    float m_i = -__builtin_inff(), l_i = 0.f;

    const int t0 = wave * 2, t1 = t0 + 1;
    const u16* kp0 = Kb + (size_t)((t0 >> 2) * 16 + l15) * D_ + (t0 & 3) * 32 + quad * 8;
    const u16* kp1 = Kb + (size_t)((t1 >> 2) * 16 + l15) * D_ + (t1 & 3) * 32 + quad * 8;
    const u16* vp0 = Vb + (size_t)((t0 >> 1) * 16 + l15) * S_ + (t0 & 1) * 32 + quad * 8;
    const u16* vp1 = Vb + (size_t)((t1 >> 1) * 16 + l15) * S_ + (t1 & 1) * 32 + quad * 8;

    const int ntiles = (qt + 1) * 2;
    for (int j = 0; j < ntiles; ++j) {
        const int kv0 = j * 64;
        __syncthreads();
        async16(kp0, &Ks[t0 * 512]);
        async16(kp1, &Ks[t1 * 512]);
        async16(vp0, &Vs[t0 * 512]);
        async16(vp1, &Vs[t1 * 512]);
        __syncthreads();

        f32x4 st[4];
        #pragma unroll
        for (int kb = 0; kb < 4; ++kb) st[kb] = zero4;
        #pragma unroll
        for (int kk = 0; kk < 4; ++kk)
            #pragma unroll
            for (int kb = 0; kb < 4; ++kb) {
                bf16x8 ak = *reinterpret_cast<const bf16x8*>(
                    &Ks[(kb * 4 + kk) * 512 + lane * 8]);
                st[kb] = MFMA_BF16(ak, bq[kk], st[kb], 0, 0, 0);
            }

        float mx = -__builtin_inff();
        if (j >= 2 * qt) {
            #pragma unroll
            for (int kb = 0; kb < 4; ++kb)
                #pragma unroll
                for (int r = 0; r < 4; ++r) {
                    float s = st[kb][r] * SCALE_;
                    if (kv0 + kb * 16 + quad * 4 + r > qg) s = -__builtin_inff();
                    st[kb][r] = s;
                    mx = fmaxf(mx, s);
                }
        } else {
            #pragma unroll
            for (int kb = 0; kb < 4; ++kb)
                #pragma unroll
                for (int r = 0; r < 4; ++r) {
                    float s = st[kb][r] * SCALE_;
                    st[kb][r] = s;
                    mx = fmaxf(mx, s);
                }
        }
        mx = fmaxf(mx, __shfl_xor(mx, 16));
        mx = fmaxf(mx, __shfl_xor(mx, 32));
        float mnew = fmaxf(m_i, mx);
        float a = __expf(m_i - mnew);
        float sum = 0.f;
        #pragma unroll
        for (int kb = 0; kb < 4; ++kb)
            #pragma unroll
            for (int r = 0; r < 4; ++r) {
                float p = __expf(st[kb][r] - mnew);
                st[kb][r] = p;
                sum += p;
            }
        sum += __shfl_xor(sum, 16);
        sum += __shfl_xor(sum, 32);
        l_i = l_i * a + sum;
        m_i = mnew;
        #pragma unroll
        for (int mi = 0; mi < 8; ++mi)
            #pragma unroll
            for (int r = 0; r < 4; ++r) o[mi][r] *= a;

        #pragma unroll
        for (int kf = 0; kf < 2; ++kf) {
            bf16x8 bp;
            u16* bh = (u16*)&bp;
            #pragma unroll
            for (int j2 = 0; j2 < 8; ++j2) {
                int src = ((quad & 1) * 2 + (j2 >> 2)) * 16 + l15;
                float v0 = __shfl(st[kf * 2 + 0][j2 & 3], src);
                float v1 = __shfl(st[kf * 2 + 1][j2 & 3], src);
                bh[j2] = f2b((lane >= 32) ? v1 : v0);
            }
            #pragma unroll
            for (int mi = 0; mi < 8; ++mi) {
                bf16x8 av = *reinterpret_cast<const bf16x8*>(
                    &Vs[(mi * 2 + kf) * 512 + lane * 8]);
                o[mi] = MFMA_BF16(av, bp, o[mi], 0, 0, 0);
            }
        }
        kp0 += 64 * D_; kp1 += 64 * D_; vp0 += 64; vp1 += 64;
    }

    float inv = 1.0f / l_i;
    size_t base = ((size_t)(b * S_ + qg)) * E_ + h * D_;
    #pragma unroll
    for (int mi = 0; mi < 8; ++mi) {
        u16 w[4];
        #pragma unroll
        for (int r = 0; r < 4; ++r) w[r] = f2b(o[mi][r] * inv);
        *reinterpret_cast<uint2*>(AO + base + mi * 16 + quad * 4) =
            *reinterpret_cast<const uint2*>(w);
    }
}

// ---------------------------------------------------------------------------
// Kernel 3: output projection, split-barrier double-buffered, f32 out.
// ---------------------------------------------------------------------------
__global__ __launch_bounds__(256)
void out_proj_gemm(const u16* __restrict__ ao, const u16* __restrict__ wob,
                   float* __restrict__ out) {
    __shared__ __align__(16) u16 As[2][8192];
    __shared__ __align__(16) u16 Bs[2][8192];
    const int tid = threadIdx.x, wave = tid >> 6, lane = tid & 63;
    const int l15 = lane & 15, quad = lane >> 4;
    const int wm = wave & 1, wn = wave >> 1;
    const int m0 = blockIdx.y * 128, n0 = blockIdx.x * 128;

    size_t aoff[4], boff[4];
    #pragma unroll
    for (int j = 0; j < 4; ++j) {
        int t = wave * 4 + j;
        int row = (t >> 1) * 16 + l15;
        int col = (t & 1) * 32 + quad * 8;
        aoff[j] = (size_t)(m0 + row) * E_ + col;
        boff[j] = (size_t)(n0 + row) * E_ + col;
    }

    f32x4 acc[4][4];
    const f32x4 zero4 = {0.f, 0.f, 0.f, 0.f};
    for (int i = 0; i < 4; ++i)
        for (int j = 0; j < 4; ++j) acc[i][j] = zero4;

    #pragma unroll
    for (int j = 0; j < 4; ++j) {
        int t = wave * 4 + j;
        async16(ao + aoff[j], &As[0][t * 512]);
        async16(wob + boff[j], &Bs[0][t * 512]);
    }
    __syncthreads();

    for (int it = 0; it < 32; ++it) {
        const int cur = it & 1, nxt = cur ^ 1;
        if (it < 31) {
            const size_t koff = (size_t)(it + 1) * 64;
            #pragma unroll
            for (int j = 0; j < 4; ++j) {
                int t = wave * 4 + j;
                async16(ao + aoff[j] + koff, &As[nxt][t * 512]);
                async16(wob + boff[j] + koff, &Bs[nxt][t * 512]);
            }
        }
        #pragma unroll
        for (int kb = 0; kb < 2; ++kb) {
            bf16x8 af[4], bfr[4];
            #pragma unroll
            for (int i = 0; i < 4; ++i) {
                af[i]  = *reinterpret_cast<const bf16x8*>(
                    &As[cur][(((wm * 4 + i) << 1) | kb) * 512 + lane * 8]);
                bfr[i] = *reinterpret_cast<const bf16x8*>(
                    &Bs[cur][(((wn * 4 + i) << 1) | kb) * 512 + lane * 8]);
            }
            #pragma unroll
            for (int mi = 0; mi < 4; ++mi)
                #pragma unroll
                for (int ni = 0; ni < 4; ++ni)
                    acc[mi][ni] = MFMA_BF16(af[mi], bfr[ni], acc[mi][ni], 0, 0, 0);
        }
        __syncthreads();
    }

    const int mb_ = m0 + wm * 64, nbase = n0 + wn * 64;
    #pragma unroll
    for (int mi = 0; mi < 4; ++mi)
        #pragma unroll
        for (int ni = 0; ni < 4; ++ni)
            #pragma unroll
            for (int r = 0; r < 4; ++r) {
                int m = mb_ + mi * 16 + quad * 4 + r;
                int n = nbase + ni * 16 + l15;
                out[(size_t)m * E_ + n] = acc[mi][ni][r];
            }
}

// ---------------------------------------------------------------------------
// Workspace (u16 offsets; 50.33 MB, proven-safe):
//   [0,        4194304): wqb (conv->qkv) -> VrT (transpose->flash) -> wob
//   [4194304, 12582912): xb  (conv->qkv) -> AO  (flash->out_proj)
//   [12582912,20971520): Qr
//   [20971520,23068672): Kr
//   [23068672,25165824): Vr
// d_out scratch (rewritten entirely by out_proj at the end):
//   [0, 1048576) u16: wkb   [1048576, 2097152) u16: wvb
// ---------------------------------------------------------------------------
extern "C" void kernel_launch(void* const* d_in, const int* in_sizes, int n_in,
                              void* d_out, int out_size, void* d_ws, size_t ws_size,
                              hipStream_t stream) {
    const float* x  = (const float*)d_in[0];
    const float* wq = (const float*)d_in[1];
    const float* wk = (const float*)d_in[2];
    const float* wv = (const float*)d_in[3];
    const float* wo = (const float*)d_in[4];
    const float* fc = (const float*)d_in[5];
    const float* fs = (const float*)d_in[6];
    float* out = (float*)d_out;

    u16* wqb = (u16*)d_ws;
    u16* xb  = wqb + 4194304;
    u16* Qr  = wqb + 12582912;
    u16* Kr  = wqb + 20971520;
    u16* Vr  = wqb + 23068672;
    u16* VrT = wqb;          // after qkv (wqb dead)
    u16* wob = wqb;          // after flash (VrT dead)
    u16* AO  = xb;           // after qkv (xb dead)
    u16* wkb = (u16*)d_out;  // d_out scratch until out_proj
    u16* wvb = wkb + 1048576;

    conv4<<<7168, 256, 0, stream>>>(x, xb, 4096, wq, wqb, 2048,
                                    wk, wkb, 512, wv, wvb);
    qkv_rope_gemm<<<dim3(NQKV / 128, M_ / 128), 256, 0, stream>>>(
        xb, wqb, wkb, wvb, fc, fs, Qr, Kr, Vr);
    transpose_v<<<dim3(S_ / 64, D_ / 64, B_ * KVH_), 256, 0, stream>>>(Vr, VrT);
    flash2<<<dim3(S_ / 128, H_, B_), 512, 0, stream>>>(Qr, Kr, VrT, AO);
    conv4<<<2048, 256, 0, stream>>>(wo, wob, 2048, nullptr, nullptr, 0,
                                    nullptr, nullptr, 0, nullptr, nullptr);
    out_proj_gemm<<<dim3(E_ / 128, M_ / 128), 256, 0, stream>>>(AO, wob, out);
}

// Round 13
// 453.126 us; speedup vs baseline: 1.1452x; 1.1452x over previous
//
#include <hip/hip_runtime.h>
#include <hip/hip_bf16.h>

typedef unsigned short u16;
typedef unsigned int u32;
typedef short bf16x8 __attribute__((ext_vector_type(8)));
typedef float f32x4 __attribute__((ext_vector_type(4)));

#define MFMA_BF16 __builtin_amdgcn_mfma_f32_16x16x32_bf16

#define B_   2
#define S_   2048
#define E_   2048
#define H_   16
#define KVH_ 4
#define D_   128
#define M_   (B_ * S_)
#define NQKV 3072
#define SCALE_ 0.08838834764831845f  // 1/sqrt(128)

__device__ __forceinline__ float b2f(u16 u) {
    union { u32 i; float f; } x; x.i = ((u32)u) << 16; return x.f;
}
__device__ __forceinline__ u16 f2b(float f) {
    __hip_bfloat16 h = __float2bfloat16(f);
    return *reinterpret_cast<u16*>(&h);
}

// async 16B global->LDS: HW writes lds_base + lane*16  [m97 pattern]
__device__ __forceinline__ void async16(const u16* g, u16* l) {
    __builtin_amdgcn_global_load_lds(
        (const __attribute__((address_space(1))) void*)g,
        (__attribute__((address_space(3))) void*)l, 16, 0, 0);
}

__device__ __forceinline__ uint4 pack8(const float* p) {
    float4 a = *reinterpret_cast<const float4*>(p);
    float4 b = *reinterpret_cast<const float4*>(p + 4);
    union { uint4 v; u16 h[8]; } pk;
    pk.h[0] = f2b(a.x); pk.h[1] = f2b(a.y); pk.h[2] = f2b(a.z); pk.h[3] = f2b(a.w);
    pk.h[4] = f2b(b.x); pk.h[5] = f2b(b.y); pk.h[6] = f2b(b.z); pk.h[7] = f2b(b.w);
    return pk.v;
}

// ---------------------------------------------------------------------------
// f32 -> bf16 bulk convert, up to 4 regions per launch (2048 elems/block).
// ---------------------------------------------------------------------------
__global__ __launch_bounds__(256)
void conv4(const float* __restrict__ s0, u16* __restrict__ d0, int n0,
           const float* __restrict__ s1, u16* __restrict__ d1, int n1,
           const float* __restrict__ s2, u16* __restrict__ d2, int n2,
           const float* __restrict__ s3, u16* __restrict__ d3) {
    int bid = blockIdx.x;
    const float* s; u16* d; size_t base;
    if (bid < n0)                { s = s0; d = d0; base = (size_t)bid * 2048; }
    else if (bid < n0 + n1)      { s = s1; d = d1; base = (size_t)(bid - n0) * 2048; }
    else if (bid < n0 + n1 + n2) { s = s2; d = d2; base = (size_t)(bid - n0 - n1) * 2048; }
    else                         { s = s3; d = d3; base = (size_t)(bid - n0 - n1 - n2) * 2048; }
    size_t i = base + (size_t)threadIdx.x * 8;
    *reinterpret_cast<uint4*>(d + i) = pack8(s + i);
}

// ---------------------------------------------------------------------------
// Kernel 1: fused QKV gemm_bt + RoPE (R11 single-buffer version -- dbuf
// regressed via occupancy loss, reverted).  128x128 tile, BK=64, 32 KB LDS,
// fragment-major (conflict-free, lane-exact async16 staging).
// ---------------------------------------------------------------------------
__global__ __launch_bounds__(256)
void qkv_rope_gemm(const u16* __restrict__ xb, const u16* __restrict__ wqb,
                   const u16* __restrict__ wkb, const u16* __restrict__ wvb,
                   const float* __restrict__ fc, const float* __restrict__ fs,
                   u16* __restrict__ Qr, u16* __restrict__ Kr,
                   u16* __restrict__ Vr) {
    __shared__ __align__(16) u16 As[8192];
    __shared__ __align__(16) u16 Bs[8192];
    const int tid = threadIdx.x, wave = tid >> 6, lane = tid & 63;
    const int l15 = lane & 15, quad = lane >> 4;
    const int wm = wave & 1, wn = wave >> 1;
    const int m0 = blockIdx.y * 128, n0 = blockIdx.x * 128;

    const u16* wsel;
    if (n0 < 2048)      wsel = wqb + (size_t)n0 * E_;
    else if (n0 < 2560) wsel = wkb + (size_t)(n0 - 2048) * E_;
    else                wsel = wvb + (size_t)(n0 - 2560) * E_;

    f32x4 acc[4][4];
    const f32x4 zero4 = {0.f, 0.f, 0.f, 0.f};
    for (int i = 0; i < 4; ++i)
        for (int j = 0; j < 4; ++j) acc[i][j] = zero4;

    for (int kt = 0; kt < E_; kt += 64) {
        __syncthreads();
        #pragma unroll
        for (int j = 0; j < 4; ++j) {
            int t = wave * 4 + j;
            int row = (t >> 1) * 16 + l15;
            int col = kt + (t & 1) * 32 + quad * 8;
            async16(xb + (size_t)(m0 + row) * E_ + col, &As[t * 512]);
            async16(wsel + (size_t)row * E_ + col, &Bs[t * 512]);
        }
        __syncthreads();
        #pragma unroll
        for (int kb = 0; kb < 2; ++kb) {
            bf16x8 af[4], bfr[4];
            #pragma unroll
            for (int i = 0; i < 4; ++i) {
                af[i]  = *reinterpret_cast<const bf16x8*>(
                    &As[(((wm * 4 + i) << 1) | kb) * 512 + lane * 8]);
                bfr[i] = *reinterpret_cast<const bf16x8*>(
                    &Bs[(((wn * 4 + i) << 1) | kb) * 512 + lane * 8]);
            }
            #pragma unroll
            for (int mi = 0; mi < 4; ++mi)
                #pragma unroll
                for (int ni = 0; ni < 4; ++ni)
                    acc[mi][ni] = MFMA_BF16(af[mi], bfr[ni], acc[mi][ni], 0, 0, 0);
        }
    }

    const int mb_ = m0 + wm * 64, nbase = n0 + wn * 64;
    #pragma unroll
    for (int mi = 0; mi < 4; ++mi)
        #pragma unroll
        for (int ni = 0; ni < 4; ++ni)
            #pragma unroll
            for (int r = 0; r < 4; ++r) {
                int m = mb_ + mi * 16 + quad * 4 + r;   // C/D: row=quad*4+reg
                int n = nbase + ni * 16 + l15;          //      col=lane&15
                int b = m >> 11, s = m & 2047;
                float v = acc[mi][ni][r];
                float other = __shfl_xor(v, 1);
                if (n < 2560) {                          // rope on q and k
                    int d = n & 127;
                    int fi = s * 64 + (d >> 1);
                    float c  = fc[fi];
                    float sn = fs[fi];
                    v = (n & 1) ? (other * sn + v * c) : (v * c - other * sn);
                }
                if (n < 2048) {
                    Qr[((size_t)(b * H_ + (n >> 7)) * S_ + s) * D_ + (n & 127)] = f2b(v);
                } else if (n < 2560) {
                    int kh = (n - 2048) >> 7;
                    Kr[((size_t)(b * KVH_ + kh) * S_ + s) * D_ + (n & 127)] = f2b(v);
                } else {
                    int kh = (n - 2560) >> 7;
                    Vr[((size_t)(b * KVH_ + kh) * S_ + s) * D_ + (n & 127)] = f2b(v);
                }
            }
}

// ---------------------------------------------------------------------------
// Kernel 1.7: V transpose per (b,kvh): Vr[s][d] -> VrT[d][s].
// ---------------------------------------------------------------------------
__global__ __launch_bounds__(256)
void transpose_v(const u16* __restrict__ Vr, u16* __restrict__ VrT) {
    __shared__ u16 t[64][72];
    const int tid = threadIdx.x;
    const int s0 = blockIdx.x * 64, d0 = blockIdx.y * 64, g = blockIdx.z;
    const u16* src = Vr + (size_t)g * S_ * D_;
    u16* dst = VrT + (size_t)g * D_ * S_;
    #pragma unroll
    for (int i = 0; i < 2; ++i) {
        int c = tid + i * 256;
        int r = c >> 3, cc = (c & 7) * 8;
        *reinterpret_cast<uint4*>(&t[r][cc]) =
            *reinterpret_cast<const uint4*>(src + (size_t)(s0 + r) * D_ + d0 + cc);
    }
    __syncthreads();
    #pragma unroll
    for (int i = 0; i < 2; ++i) {
        int c = tid + i * 256;
        int r = c >> 3, cc = (c & 7) * 8;
        u16 tmp[8];
        #pragma unroll
        for (int e = 0; e < 8; ++e) tmp[e] = t[cc + e][r];
        *reinterpret_cast<uint4*>(dst + (size_t)(d0 + r) * S_ + s0 + cc) =
            *reinterpret_cast<const uint4*>(tmp);
    }
}

// ---------------------------------------------------------------------------
// Kernel 2: transposed causal flash attention v2.
// kv MACRO-TILE 128 staged per barrier pair (half the barriers of R11);
// inner loop processes two 64-kv halves reusing st[4] (no VGPR growth).
// P C->B-frag conversion via PACKED shuffles: both kb candidates packed in
// one u32 before shfl, half extracted by quad>>1 after (8 shfl + 8 f2b per
// kf instead of 16+16).  Fully-masked halves skipped wave-uniformly.
// GQA per jnp.tile: kvh = h % KVH.
// ---------------------------------------------------------------------------
__global__ __launch_bounds__(512, 4)
void flash2(const u16* __restrict__ Qr, const u16* __restrict__ Kr,
            const u16* __restrict__ VrT, u16* __restrict__ AO) {
    __shared__ __align__(16) u16 Ks[128 * 128];   // 32 frags of 512 elems
    __shared__ __align__(16) u16 Vs[128 * 128];   // 32 frags of 512 elems
    const int tid = threadIdx.x, wave = tid >> 6, lane = tid & 63;
    const int l15 = lane & 15, quad = lane >> 4;
    const int qt = blockIdx.x, h = blockIdx.y, b = blockIdx.z;
    const int kvh = h & 3;                        // jnp.tile mapping
    const u16* Qb = Qr + (size_t)(b * H_ + h) * S_ * D_;
    const u16* Kb = Kr + (size_t)(b * KVH_ + kvh) * S_ * D_;
    const u16* Vb = VrT + (size_t)(b * KVH_ + kvh) * D_ * S_;
    const int q0 = qt * 128 + wave * 16;
    const int qg = q0 + l15;                      // this lane's q row

    // Q as B-operand (n=q=l15, k=quad*8+j), register-resident
    bf16x8 bq[4];
    #pragma unroll
    for (int kk = 0; kk < 4; ++kk)
        bq[kk] = *reinterpret_cast<const bf16x8*>(
            Qb + (size_t)qg * D_ + kk * 32 + quad * 8);

    f32x4 o[8];
    const f32x4 zero4 = {0.f, 0.f, 0.f, 0.f};
    #pragma unroll
    for (int i = 0; i < 8; ++i) o[i] = zero4;
    float m_i = -__builtin_inff(), l_i = 0.f;

    // staging: each wave stages 4 K frags + 4 V frags of the 128-kv tile.
    // K frag t: kv=(t>>2)*16+l15, d=(t&3)*32+quad*8
    // V frag t: d =(t>>2)*16+l15, kv=(t&3)*32+quad*8
    const u16* kp[4]; const u16* vp[4];
    #pragma unroll
    for (int jj = 0; jj < 4; ++jj) {
        int t = wave * 4 + jj;
        kp[jj] = Kb + (size_t)((t >> 2) * 16 + l15) * D_ + (t & 3) * 32 + quad * 8;
        vp[jj] = Vb + (size_t)((t >> 2) * 16 + l15) * S_ + (t & 3) * 32 + quad * 8;
    }

    const int ntiles = qt + 1;                    // 128-kv macro tiles
    for (int j = 0; j < ntiles; ++j) {
        __syncthreads();                          // prev-tile reads done
        #pragma unroll
        for (int jj = 0; jj < 4; ++jj) {
            int t = wave * 4 + jj;
            async16(kp[jj], &Ks[t * 512]);
            async16(vp[jj], &Vs[t * 512]);
        }
        __syncthreads();                          // staging visible

        #pragma unroll
        for (int h2 = 0; h2 < 2; ++h2) {
            const int kvbase = j * 128 + h2 * 64;
            if (q0 + 15 < kvbase) continue;       // wave-uniform skip

            // S^T[kv 64][q 16]
            f32x4 st[4];
            #pragma unroll
            for (int kb = 0; kb < 4; ++kb) st[kb] = zero4;
            #pragma unroll
            for (int kk = 0; kk < 4; ++kk)
                #pragma unroll
                for (int kb = 0; kb < 4; ++kb) {
                    bf16x8 ak = *reinterpret_cast<const bf16x8*>(
                        &Ks[(((h2 * 4 + kb) << 2) | kk) * 512 + lane * 8]);
                    st[kb] = MFMA_BF16(ak, bq[kk], st[kb], 0, 0, 0);
                }

            // online softmax (lane owns one q col; kv over kb,quad,reg)
            float mx = -__builtin_inff();
            if (j == qt) {                        // diagonal: mask
                #pragma unroll
                for (int kb = 0; kb < 4; ++kb)
                    #pragma unroll
                    for (int r = 0; r < 4; ++r) {
                        float s = st[kb][r] * SCALE_;
                        if (kvbase + kb * 16 + quad * 4 + r > qg)
                            s = -__builtin_inff();
                        st[kb][r] = s;
                        mx = fmaxf(mx, s);
                    }
            } else {
                #pragma unroll
                for (int kb = 0; kb < 4; ++kb)
                    #pragma unroll
                    for (int r = 0; r < 4; ++r) {
                        float s = st[kb][r] * SCALE_;
                        st[kb][r] = s;
                        mx = fmaxf(mx, s);
                    }
            }
            mx = fmaxf(mx, __shfl_xor(mx, 16));
            mx = fmaxf(mx, __shfl_xor(mx, 32));
            float mnew = fmaxf(m_i, mx);
            float a = __expf(m_i - mnew);
            float sum = 0.f;
            #pragma unroll
            for (int kb = 0; kb < 4; ++kb)
                #pragma unroll
                for (int r = 0; r < 4; ++r) {
                    float p = __expf(st[kb][r] - mnew);
                    st[kb][r] = p;
                    sum += p;
                }
            sum += __shfl_xor(sum, 16);
            sum += __shfl_xor(sum, 32);
            l_i = l_i * a + sum;
            m_i = mnew;
            #pragma unroll
            for (int mi = 0; mi < 8; ++mi)
                #pragma unroll
                for (int r = 0; r < 4; ++r) o[mi][r] *= a;

            // P -> B-frag via packed shuffles; O^T += V^T P^T
            #pragma unroll
            for (int kf = 0; kf < 2; ++kf) {
                u32 pk[4];
                #pragma unroll
                for (int r = 0; r < 4; ++r)
                    pk[r] = (u32)f2b(st[kf * 2 + 0][r]) |
                            ((u32)f2b(st[kf * 2 + 1][r]) << 16);
                bf16x8 bp;
                u16* bh = (u16*)&bp;
                #pragma unroll
                for (int j2 = 0; j2 < 8; ++j2) {
                    int src = ((quad & 1) * 2 + (j2 >> 2)) * 16 + l15;
                    u32 v = __shfl((int)pk[j2 & 3], src);
                    bh[j2] = (lane >= 32) ? (u16)(v >> 16) : (u16)v;
                }
                #pragma unroll
                for (int mi = 0; mi < 8; ++mi) {
                    bf16x8 av = *reinterpret_cast<const bf16x8*>(
                        &Vs[(((mi << 2) | (h2 * 2 + kf)) * 512) + lane * 8]);
                    o[mi] = MFMA_BF16(av, bp, o[mi], 0, 0, 0);
                }
            }
        }
        #pragma unroll
        for (int jj = 0; jj < 4; ++jj) { kp[jj] += 128 * D_; vp[jj] += 128; }
    }

    // epilogue: O^T[d][q], lane holds d = mi*16+quad*4+r for its q
    float inv = 1.0f / l_i;
    size_t base = ((size_t)(b * S_ + qg)) * E_ + h * D_;
    #pragma unroll
    for (int mi = 0; mi < 8; ++mi) {
        u16 w[4];
        #pragma unroll
        for (int r = 0; r < 4; ++r) w[r] = f2b(o[mi][r] * inv);
        *reinterpret_cast<uint2*>(AO + base + mi * 16 + quad * 4) =
            *reinterpret_cast<const uint2*>(w);
    }
}

// ---------------------------------------------------------------------------
// Kernel 3: output projection (R11 single-buffer version), f32 out.
// ---------------------------------------------------------------------------
__global__ __launch_bounds__(256)
void out_proj_gemm(const u16* __restrict__ ao, const u16* __restrict__ wob,
                   float* __restrict__ out) {
    __shared__ __align__(16) u16 As[8192];
    __shared__ __align__(16) u16 Bs[8192];
    const int tid = threadIdx.x, wave = tid >> 6, lane = tid & 63;
    const int l15 = lane & 15, quad = lane >> 4;
    const int wm = wave & 1, wn = wave >> 1;
    const int m0 = blockIdx.y * 128, n0 = blockIdx.x * 128;

    f32x4 acc[4][4];
    const f32x4 zero4 = {0.f, 0.f, 0.f, 0.f};
    for (int i = 0; i < 4; ++i)
        for (int j = 0; j < 4; ++j) acc[i][j] = zero4;

    for (int kt = 0; kt < E_; kt += 64) {
        __syncthreads();
        #pragma unroll
        for (int j = 0; j < 4; ++j) {
            int t = wave * 4 + j;
            int row = (t >> 1) * 16 + l15;
            int col = kt + (t & 1) * 32 + quad * 8;
            async16(ao  + (size_t)(m0 + row) * E_ + col, &As[t * 512]);
            async16(wob + (size_t)(n0 + row) * E_ + col, &Bs[t * 512]);
        }
        __syncthreads();
        #pragma unroll
        for (int kb = 0; kb < 2; ++kb) {
            bf16x8 af[4], bfr[4];
            #pragma unroll
            for (int i = 0; i < 4; ++i) {
                af[i]  = *reinterpret_cast<const bf16x8*>(
                    &As[(((wm * 4 + i) << 1) | kb) * 512 + lane * 8]);
                bfr[i] = *reinterpret_cast<const bf16x8*>(
                    &Bs[(((wn * 4 + i) << 1) | kb) * 512 + lane * 8]);
            }
            #pragma unroll
            for (int mi = 0; mi < 4; ++mi)
                #pragma unroll
                for (int ni = 0; ni < 4; ++ni)
                    acc[mi][ni] = MFMA_BF16(af[mi], bfr[ni], acc[mi][ni], 0, 0, 0);
        }
    }

    const int mb_ = m0 + wm * 64, nbase = n0 + wn * 64;
    #pragma unroll
    for (int mi = 0; mi < 4; ++mi)
        #pragma unroll
        for (int ni = 0; ni < 4; ++ni)
            #pragma unroll
            for (int r = 0; r < 4; ++r) {
                int m = mb_ + mi * 16 + quad * 4 + r;
                int n = nbase + ni * 16 + l15;
                out[(size_t)m * E_ + n] = acc[mi][ni][r];
            }
}

// ---------------------------------------------------------------------------
// Workspace (u16 offsets; 50.33 MB, proven-safe):
//   [0,        4194304): wqb (conv->qkv) -> VrT (transpose->flash) -> wob
//   [4194304, 12582912): xb  (conv->qkv) -> AO  (flash->out_proj)
//   [12582912,20971520): Qr
//   [20971520,23068672): Kr
//   [23068672,25165824): Vr
// d_out scratch (rewritten entirely by out_proj at the end):
//   [0, 1048576) u16: wkb   [1048576, 2097152) u16: wvb
// ---------------------------------------------------------------------------
extern "C" void kernel_launch(void* const* d_in, const int* in_sizes, int n_in,
                              void* d_out, int out_size, void* d_ws, size_t ws_size,
                              hipStream_t stream) {
    const float* x  = (const float*)d_in[0];
    const float* wq = (const float*)d_in[1];
    const float* wk = (const float*)d_in[2];
    const float* wv = (const float*)d_in[3];
    const float* wo = (const float*)d_in[4];
    const float* fc = (const float*)d_in[5];
    const float* fs = (const float*)d_in[6];
    float* out = (float*)d_out;

    u16* wqb = (u16*)d_ws;
    u16* xb  = wqb + 4194304;
    u16* Qr  = wqb + 12582912;
    u16* Kr  = wqb + 20971520;
    u16* Vr  = wqb + 23068672;
    u16* VrT = wqb;          // after qkv (wqb dead)
    u16* wob = wqb;          // after flash (VrT dead)
    u16* AO  = xb;           // after qkv (xb dead)
    u16* wkb = (u16*)d_out;  // d_out scratch until out_proj
    u16* wvb = wkb + 1048576;

    conv4<<<7168, 256, 0, stream>>>(x, xb, 4096, wq, wqb, 2048,
                                    wk, wkb, 512, wv, wvb);
    qkv_rope_gemm<<<dim3(NQKV / 128, M_ / 128), 256, 0, stream>>>(
        xb, wqb, wkb, wvb, fc, fs, Qr, Kr, Vr);
    transpose_v<<<dim3(S_ / 64, D_ / 64, B_ * KVH_), 256, 0, stream>>>(Vr, VrT);
    flash2<<<dim3(S_ / 128, H_, B_), 512, 0, stream>>>(Qr, Kr, VrT, AO);
    conv4<<<2048, 256, 0, stream>>>(wo, wob, 2048, nullptr, nullptr, 0,
                                    nullptr, nullptr, 0, nullptr, nullptr);
    out_proj_gemm<<<dim3(E_ / 128, M_ / 128), 256, 0, stream>>>(AO, wob, out);
}